// Round 2
// baseline (251.934 us; speedup 1.0000x reference)
//
#include <hip/hip_runtime.h>

// Sort_Latent_Layer: per row of (4096, 8192) fp32, view as 512 packets of 16,
// stable-argsort packets by first element, emit packets in sorted order.
//
// R2 design: one WAVE per row (4 rows per 256-thread block). Barrier-free
// rank sort: each lane holds 8 composite u64 keys (orderable-float-bits:32 |
// packet-idx:9 => single u64 compare gives stable order). Rank = count of
// smaller keys via LDS broadcast reads (no bank conflicts). Inverse perm in
// LDS, then gather packets from global (row stays L2/L3-resident) with fully
// coalesced float4 stores. LDS = 20 KB/block -> 8 blocks/CU, 32 waves (100%).

#define NPK 512       // packets per row
#define DIM 8192      // floats per row
#define RPB 4         // rows (waves) per block
#define NT  256       // threads per block

__global__ __launch_bounds__(NT, 8)
void sort_latent_kernel(const float* __restrict__ z, float* __restrict__ out) {
    __shared__ unsigned long long keys[RPB][NPK];   // 16 KB
    __shared__ unsigned short     srcp[RPB][NPK];   // 4 KB

    const int lane = threadIdx.x & 63;
    const int w    = threadIdx.x >> 6;                 // wave id = row-in-block
    const int row  = blockIdx.x * RPB + w;
    const float* __restrict__ rowin  = z   + (size_t)row * DIM;
    float*       __restrict__ rowout = out + (size_t)row * DIM;

    // ---- Phase 1: load 8 keys/lane (first float of each 64B packet),
    //      convert to order-preserving u32, compose stable u64 key ----
    unsigned long long myk[8];
#pragma unroll
    for (int i = 0; i < 8; ++i) {
        const unsigned int p = (unsigned)(i * 64 + lane);
        const unsigned int b = __float_as_uint(rowin[p * 16]);
        // negatives -> ~b (reversed), positives -> b | signbit: total order
        const unsigned int u = b ^ (((unsigned)((int)b >> 31)) | 0x80000000u);
        myk[i] = ((unsigned long long)u << 32) | p;    // tie-break on p: stable
        keys[w][p] = myk[i];
    }
    __syncthreads();

    // ---- Phase 2: rank my 8 packets against all 512 (barrier-free) ----
    unsigned int rank[8] = {0, 0, 0, 0, 0, 0, 0, 0};
    const unsigned long long* __restrict__ kk = keys[w];
    for (int j = 0; j < NPK; j += 2) {                 // ds_read_b128 broadcast
        const unsigned long long k0 = kk[j];
        const unsigned long long k1 = kk[j + 1];
#pragma unroll
        for (int i = 0; i < 8; ++i) {
            rank[i] += (unsigned)(k0 < myk[i]);
            rank[i] += (unsigned)(k1 < myk[i]);
        }
    }
    // inverse permutation: output slot rank[i] takes input packet p_i
#pragma unroll
    for (int i = 0; i < 8; ++i)
        srcp[w][rank[i]] = (unsigned short)(i * 64 + lane);
    __syncthreads();

    // ---- Phase 3: gather packets via L2/L3; coalesced float4 stores ----
    const float4* __restrict__ in4  = (const float4*)rowin;
    float4*       __restrict__ out4 = (float4*)rowout;
#pragma unroll 8
    for (int i = 0; i < DIM / 4 / 64; ++i) {           // 32 iterations
        const int o = i * 64 + lane;                   // dest float4 slot
        const int s = (int)srcp[w][o >> 2];            // source packet
        out4[o] = in4[(s << 2) | (o & 3)];
    }
}

extern "C" void kernel_launch(void* const* d_in, const int* in_sizes, int n_in,
                              void* d_out, int out_size, void* d_ws, size_t ws_size,
                              hipStream_t stream) {
    const float* z = (const float*)d_in[0];
    float* out = (float*)d_out;
    const int nrows = in_sizes[0] / DIM;               // 4096
    sort_latent_kernel<<<nrows / RPB, NT, 0, stream>>>(z, out);
}

// Round 3
// 250.914 us; speedup vs baseline: 1.0041x; 1.0041x over previous
//
#include <hip/hip_runtime.h>

// Sort_Latent_Layer: per row of (4096, 8192) fp32, view as 512 packets of 16,
// stable-argsort packets by first element, emit packets in sorted order.
//
// R3: one WAVE per row. Bitonic sort of 512 composite u64 keys held entirely
// in registers (8/lane x 64 lanes). Element e = lane*8 + r. Steps with
// j >= 8 exchange across lanes via __shfl_xor (distance j/8, no barrier);
// j < 8 are in-register compare-exchanges. Composite key =
// (order-preserving f32 bits << 32) | packet_idx -> single u64 compare is
// stable (matches jnp.argsort). Then gather packets via L2/L3 with coalesced
// float4 stores, exactly as R2's (memory-efficient) epilogue.

#define NPK 512       // packets per row
#define DIM 8192      // floats per row
#define RPB 4         // rows (waves) per block
#define NT  256       // threads per block

typedef unsigned long long u64;

// compare-exchange: after, (a,b) ascending if up, descending if !up.
// keys are unique (idx embedded) so no equality case.
#define CEX(a, b, up) {                      \
    bool sw = ((a) > (b)) == (up);           \
    u64 t0 = sw ? (b) : (a);                 \
    (b) = sw ? (a) : (b);                    \
    (a) = t0;                                \
}

__global__ __launch_bounds__(NT, 8)
void sort_latent_kernel(const float* __restrict__ z, float* __restrict__ out) {
    __shared__ unsigned short srcp[RPB][NPK];   // 4 KB: sorted-pos -> src packet

    const int lane = threadIdx.x & 63;
    const int w    = threadIdx.x >> 6;
    const int row  = blockIdx.x * RPB + w;
    const float* __restrict__ rowin  = z   + (size_t)row * DIM;
    float*       __restrict__ rowout = out + (size_t)row * DIM;

    // ---- Load 8 keys/lane, build composite stable keys ----
    u64 v[8];
#pragma unroll
    for (int r = 0; r < 8; ++r) {
        const unsigned p = (unsigned)(lane * 8 + r);
        const unsigned b = __float_as_uint(rowin[p * 16]);
        const unsigned u = b ^ (((unsigned)((int)b >> 31)) | 0x80000000u);
        v[r] = ((u64)u << 32) | p;
    }

    // ---- Bitonic network over e = lane*8 + r, ascending overall ----
    // k=2 (j=1): up = ((r & 2) == 0)
    CEX(v[0], v[1], true);  CEX(v[2], v[3], false);
    CEX(v[4], v[5], true);  CEX(v[6], v[7], false);
    // k=4, j=2: up = ((r & 4) == 0)
    CEX(v[0], v[2], true);  CEX(v[1], v[3], true);
    CEX(v[4], v[6], false); CEX(v[5], v[7], false);
    // k=4, j=1
    CEX(v[0], v[1], true);  CEX(v[2], v[3], true);
    CEX(v[4], v[5], false); CEX(v[6], v[7], false);

    // k = 8 .. 512
    for (int k = 8; k <= NPK; k <<= 1) {
        const bool up = ((lane & (k >> 3)) == 0);   // bit of e in lane field
        for (int j = k >> 1; j >= 8; j >>= 1) {     // cross-lane steps
            const int d = j >> 3;
            const bool keepmin = (((lane & d) == 0) == up);
#pragma unroll
            for (int r = 0; r < 8; ++r) {
                const u64 o = __shfl_xor(v[r], d, 64);
                const u64 mn = (v[r] < o) ? v[r] : o;
                const u64 mx = v[r] ^ o ^ mn;
                v[r] = keepmin ? mn : mx;
            }
        }
        // in-lane sweep j=4,2,1 (direction uniform across regs for k>=8)
        CEX(v[0], v[4], up); CEX(v[1], v[5], up);
        CEX(v[2], v[6], up); CEX(v[3], v[7], up);
        CEX(v[0], v[2], up); CEX(v[1], v[3], up);
        CEX(v[4], v[6], up); CEX(v[5], v[7], up);
        CEX(v[0], v[1], up); CEX(v[2], v[3], up);
        CEX(v[4], v[5], up); CEX(v[6], v[7], up);
    }

    // ---- Publish permutation: sorted position e gets packet (v[r] & 511) ----
#pragma unroll
    for (int r = 0; r < 8; ++r)
        srcp[w][lane * 8 + r] = (unsigned short)(v[r] & (NPK - 1));
    __syncthreads();

    // ---- Gather packets via L2/L3; coalesced float4 stores ----
    const float4* __restrict__ in4  = (const float4*)rowin;
    float4*       __restrict__ out4 = (float4*)rowout;
#pragma unroll 8
    for (int i = 0; i < DIM / 4 / 64; ++i) {       // 32 iterations
        const int o = i * 64 + lane;               // dest float4 slot
        const int s = (int)srcp[w][o >> 2];        // source packet
        out4[o] = in4[(s << 2) | (o & 3)];
    }
}

extern "C" void kernel_launch(void* const* d_in, const int* in_sizes, int n_in,
                              void* d_out, int out_size, void* d_ws, size_t ws_size,
                              hipStream_t stream) {
    const float* z = (const float*)d_in[0];
    float* out = (float*)d_out;
    const int nrows = in_sizes[0] / DIM;           // 4096
    sort_latent_kernel<<<nrows / RPB, NT, 0, stream>>>(z, out);
}